// Round 2
// baseline (267.648 us; speedup 1.0000x reference)
//
#include <hip/hip_runtime.h>
#include <cstdint>

#define N_NODES 50000
#define N_EDGES 800000
#define F_IN    128
#define N_HEADS 4
#define HEAD_DIM 32
#define F_OUT   128
#define NBLK_SCAN 196                     // ceil(50000/256)
#define GEMM_GRID ((N_NODES + 127) / 128) // 391

typedef unsigned int  uint32;
typedef unsigned short ushort16;

__device__ __forceinline__ unsigned short f2bf(float f) {
    uint32 u = __float_as_uint(f);
    uint32 r = (u + 0x7FFFu + ((u >> 16) & 1u)) >> 16;   // RNE
    return (unsigned short)r;
}

// ---------------------------------------------------------------------------
// K1: h = x @ W (fp32 accum, bf16 output), fused alpha_l/alpha_r epilogue,
// fused in-degree histogram (edge atomics overlap GEMM compute).
// Block = 256, tile = 128x128, BK = 64. Thread (c=t&15, g=t>>4) computes rows
// 8g..8g+7, cols {4c..4c+3, 64+4c..67+4c}. x staged transposed in LDS.
// ---------------------------------------------------------------------------
__global__ __launch_bounds__(256) void k_gemm_alpha(
    const float* __restrict__ x, const float* __restrict__ W,
    const float* __restrict__ attl, const float* __restrict__ attr,
    const int* __restrict__ ei_to, int* __restrict__ count,
    unsigned short* __restrict__ hb, float* __restrict__ aL, float* __restrict__ aR)
{
    // fused edge histogram: independent of GEMM data, latency hidden
    for (int e = blockIdx.x * 256 + threadIdx.x; e < N_EDGES; e += GEMM_GRID * 256)
        atomicAdd(&count[ei_to[e]], 1);

    __shared__ float Wl[64 * 128];   // Wl[kk][col]
    __shared__ float xT[64 * 128];   // xT[kk][row]
    const int t = threadIdx.x;
    const int row0 = blockIdx.x * 128;

    const int c = t & 15;
    const int g = t >> 4;

    float4 acc0[8], acc1[8];
#pragma unroll
    for (int r = 0; r < 8; ++r) {
        acc0[r] = make_float4(0.f, 0.f, 0.f, 0.f);
        acc1[r] = make_float4(0.f, 0.f, 0.f, 0.f);
    }

    const int wc4  = t & 31;
    const int wkk0 = t >> 5;
    const int xr8  = t & 7;
    const int xc16 = (t >> 3) & 15;
    const int xrh  = t >> 7;

    for (int kt = 0; kt < 128; kt += 64) {
        if (kt) __syncthreads();
#pragma unroll
        for (int i = 0; i < 8; ++i) {
            int kk = wkk0 + 8 * i;
            float4 w = *(const float4*)&W[(kt + kk) * F_OUT + 4 * wc4];
            *(float4*)&Wl[kk * 128 + 4 * wc4] = w;
        }
#pragma unroll
        for (int i = 0; i < 8; ++i) {
            int r = xr8 + 8 * xrh + 16 * i;
            int grow = row0 + r;
            float4 v = make_float4(0.f, 0.f, 0.f, 0.f);
            if (grow < N_NODES) v = *(const float4*)&x[grow * F_IN + kt + 4 * xc16];
            xT[(4 * xc16 + 0) * 128 + r] = v.x;
            xT[(4 * xc16 + 1) * 128 + r] = v.y;
            xT[(4 * xc16 + 2) * 128 + r] = v.z;
            xT[(4 * xc16 + 3) * 128 + r] = v.w;
        }
        __syncthreads();

#pragma unroll 4
        for (int k = 0; k < 64; ++k) {
            float4 xa = *(float4*)&xT[k * 128 + 8 * g];
            float4 xb = *(float4*)&xT[k * 128 + 8 * g + 4];
            float4 wa = *(float4*)&Wl[k * 128 + 4 * c];
            float4 wb = *(float4*)&Wl[k * 128 + 64 + 4 * c];
            float xr[8] = {xa.x, xa.y, xa.z, xa.w, xb.x, xb.y, xb.z, xb.w};
#pragma unroll
            for (int r = 0; r < 8; ++r) {
                acc0[r].x = fmaf(xr[r], wa.x, acc0[r].x);
                acc0[r].y = fmaf(xr[r], wa.y, acc0[r].y);
                acc0[r].z = fmaf(xr[r], wa.z, acc0[r].z);
                acc0[r].w = fmaf(xr[r], wa.w, acc0[r].w);
                acc1[r].x = fmaf(xr[r], wb.x, acc1[r].x);
                acc1[r].y = fmaf(xr[r], wb.y, acc1[r].y);
                acc1[r].z = fmaf(xr[r], wb.z, acc1[r].z);
                acc1[r].w = fmaf(xr[r], wb.w, acc1[r].w);
            }
        }
    }

    // epilogue: alphas from exact fp32 accumulators; h stored bf16
    const int h0 = c >> 3;
    const int h1 = 2 + (c >> 3);
    const int d0 = (c & 7) * 4;
    const float4 al0 = *(const float4*)&attl[h0 * HEAD_DIM + d0];
    const float4 al1 = *(const float4*)&attl[h1 * HEAD_DIM + d0];
    const float4 ar0 = *(const float4*)&attr[h0 * HEAD_DIM + d0];
    const float4 ar1 = *(const float4*)&attr[h1 * HEAD_DIM + d0];

#pragma unroll
    for (int r = 0; r < 8; ++r) {
        int row = row0 + 8 * g + r;
        float pl0 = acc0[r].x * al0.x + acc0[r].y * al0.y + acc0[r].z * al0.z + acc0[r].w * al0.w;
        float pr0 = acc0[r].x * ar0.x + acc0[r].y * ar0.y + acc0[r].z * ar0.z + acc0[r].w * ar0.w;
        float pl1 = acc1[r].x * al1.x + acc1[r].y * al1.y + acc1[r].z * al1.z + acc1[r].w * al1.w;
        float pr1 = acc1[r].x * ar1.x + acc1[r].y * ar1.y + acc1[r].z * ar1.z + acc1[r].w * ar1.w;
#pragma unroll
        for (int d = 1; d < 8; d <<= 1) {
            pl0 += __shfl_xor(pl0, d);
            pr0 += __shfl_xor(pr0, d);
            pl1 += __shfl_xor(pl1, d);
            pr1 += __shfl_xor(pr1, d);
        }
        if (row < N_NODES) {
            ushort4 b0, b1;
            b0.x = f2bf(acc0[r].x); b0.y = f2bf(acc0[r].y);
            b0.z = f2bf(acc0[r].z); b0.w = f2bf(acc0[r].w);
            b1.x = f2bf(acc1[r].x); b1.y = f2bf(acc1[r].y);
            b1.z = f2bf(acc1[r].z); b1.w = f2bf(acc1[r].w);
            *(ushort4*)&hb[row * F_OUT + 4 * c]      = b0;
            *(ushort4*)&hb[row * F_OUT + 64 + 4 * c] = b1;
            if ((c & 7) == 0) {
                aL[row * N_HEADS + h0] = pl0;
                aL[row * N_HEADS + h1] = pl1;
                aR[row * N_HEADS + h0] = pr0;
                aR[row * N_HEADS + h1] = pr1;
            }
        }
    }
}

// ---------------------------------------------------------------------------
// 2-level exclusive scan over 50000 counts
// ---------------------------------------------------------------------------
__device__ __forceinline__ int block_scan_excl_256(int v, int* p_total)
{
    const int t = threadIdx.x, lane = t & 63, wv = t >> 6;
    int incl = v;
#pragma unroll
    for (int d = 1; d < 64; d <<= 1) {
        int u = __shfl_up(incl, d);
        if (lane >= d) incl += u;
    }
    __shared__ int wsum[4];
    if (lane == 63) wsum[wv] = incl;
    __syncthreads();
    int woff = 0;
#pragma unroll
    for (int j = 0; j < 4; ++j) {
        int s = wsum[j];
        if (j < wv) woff += s;
    }
    if (p_total) *p_total = wsum[0] + wsum[1] + wsum[2] + wsum[3];
    __syncthreads();
    return woff + incl - v;
}

__global__ __launch_bounds__(256) void k_scan1(const int* __restrict__ count,
                                               int* __restrict__ scanned,
                                               int* __restrict__ blocksum)
{
    int i = blockIdx.x * 256 + threadIdx.x;
    int v = (i < N_NODES) ? count[i] : 0;
    int tot;
    int ex = block_scan_excl_256(v, &tot);
    if (i < N_NODES) scanned[i] = ex;
    if (threadIdx.x == 0) blocksum[blockIdx.x] = tot;
}

__global__ __launch_bounds__(256) void k_scan2(const int* __restrict__ blocksum,
                                               int* __restrict__ blockoff)
{
    int t = threadIdx.x;
    int v = (t < NBLK_SCAN) ? blocksum[t] : 0;
    int ex = block_scan_excl_256(v, nullptr);
    if (t < NBLK_SCAN) blockoff[t] = ex;
}

__global__ __launch_bounds__(256) void k_scan3(const int* __restrict__ scanned,
                                               const int* __restrict__ blockoff,
                                               int* __restrict__ offsets,
                                               int* __restrict__ cursor)
{
    int i = blockIdx.x * 256 + threadIdx.x;
    if (i < N_NODES) {
        int off = scanned[i] + blockoff[blockIdx.x];
        offsets[i] = off;
        cursor[i]  = off;
    }
}

// ---------------------------------------------------------------------------
// K4: scatter edge source ids into destination-sorted CSR order.
// (ex recomputed in the aggregation kernel — no per-edge payload.)
// ---------------------------------------------------------------------------
__global__ __launch_bounds__(256) void k_scatter(const int* __restrict__ ei,
    int* __restrict__ cursor, int* __restrict__ rec_from)
{
    int e = blockIdx.x * 256 + threadIdx.x;
    if (e >= N_EDGES) return;
    int from = ei[e], to = ei[N_EDGES + e];
    int pos = atomicAdd(&cursor[to], 1);
    rec_from[pos] = from;
}

// ---------------------------------------------------------------------------
// K5: pull aggregation, one wave per node, lane owns 2 dims (bf16 h gather).
// Softmax max-shift cancels in ex/sum(ex); att <= ~10 so no fp32 overflow.
// out[n] = (sum_e ex_e * h[from_e]) / (sum_e ex_e + 1e-9) + bias
// ---------------------------------------------------------------------------
__global__ __launch_bounds__(256) void k_agg(const int* __restrict__ rec_from,
    const int* __restrict__ count, const int* __restrict__ offsets,
    const float* __restrict__ aL, const float* __restrict__ aR,
    const unsigned short* __restrict__ hb,
    const float* __restrict__ bias, float* __restrict__ out)
{
    const int lane = threadIdx.x & 63;
    const int n = blockIdx.x * 4 + (threadIdx.x >> 6);
    if (n >= N_NODES) return;
    const int cnt = count[n];
    const int off = offsets[n];
    const int head = lane >> 4;               // (2*lane)/32
    const float arv = aR[n * N_HEADS + head]; // uniform within head group
    float ax = 0.f, ay = 0.f, ds = 0.f;
    for (int base = 0; base < cnt; base += 64) {
        const int m = min(64, cnt - base);
        int vf = 0;
        if (lane < m) vf = rec_from[off + base + lane];   // coalesced preload
        for (int i = 0; i < m; ++i) {
            const int fi = __shfl(vf, i);
            float a = aL[fi * N_HEADS + head] + arv;      // 16-B line, broadcast
            a = (a > 0.f) ? a : 0.2f * a;
            const float eh = __expf(a);
            const uint32 hv = *(const uint32*)&hb[fi * F_OUT + 2 * lane];
            const float hx = __uint_as_float(hv << 16);
            const float hy = __uint_as_float(hv & 0xFFFF0000u);
            ax = fmaf(eh, hx, ax);
            ay = fmaf(eh, hy, ay);
            ds += eh;
        }
    }
    const float inv = 1.0f / (ds + 1e-9f);
    const float2 b2 = *(const float2*)&bias[2 * lane];
    float2 o;
    o.x = ax * inv + b2.x;
    o.y = ay * inv + b2.y;
    *(float2*)&out[n * F_OUT + 2 * lane] = o;
}

// ---------------------------------------------------------------------------
extern "C" void kernel_launch(void* const* d_in, const int* in_sizes, int n_in,
                              void* d_out, int out_size, void* d_ws, size_t ws_size,
                              hipStream_t stream)
{
    const float* x    = (const float*)d_in[0];
    const int*   ei   = (const int*)d_in[1];
    const float* W    = (const float*)d_in[2];
    const float* attl = (const float*)d_in[3];
    const float* attr = (const float*)d_in[4];
    const float* bias = (const float*)d_in[5];
    float* out = (float*)d_out;

    char* p = (char*)d_ws;
    auto carve = [&](size_t bytes) -> char* {
        char* q = p;
        p += (bytes + 255) & ~size_t(255);
        return q;
    };
    unsigned short* hb = (unsigned short*)carve((size_t)N_NODES * F_OUT * 2); // 12.8 MB
    float*  aL       = (float*)carve((size_t)N_NODES * N_HEADS * 4);
    float*  aR       = (float*)carve((size_t)N_NODES * N_HEADS * 4);
    int*    count    = (int*)carve((size_t)N_NODES * 4);
    int*    scanned  = (int*)carve((size_t)N_NODES * 4);
    int*    offsets  = (int*)carve((size_t)N_NODES * 4);
    int*    cursor   = (int*)carve((size_t)N_NODES * 4);
    int*    blocksum = (int*)carve(256 * 4);
    int*    blockoff = (int*)carve(256 * 4);
    int*    rec_from = (int*)carve((size_t)N_EDGES * 4);                      // 3.2 MB

    hipMemsetAsync(count, 0, N_NODES * 4, stream);

    k_gemm_alpha<<<GEMM_GRID, 256, 0, stream>>>(x, W, attl, attr,
                                                ei + N_EDGES, count, hb, aL, aR);
    k_scan1<<<NBLK_SCAN, 256, 0, stream>>>(count, scanned, blocksum);
    k_scan2<<<1, 256, 0, stream>>>(blocksum, blockoff);
    k_scan3<<<NBLK_SCAN, 256, 0, stream>>>(scanned, blockoff, offsets, cursor);
    k_scatter<<<(N_EDGES + 255) / 256, 256, 0, stream>>>(ei, cursor, rec_from);
    k_agg<<<(N_NODES + 3) / 4, 256, 0, stream>>>(rec_from, count, offsets,
                                                 aL, aR, hb, bias, out);
}